// Round 11
// baseline (1315.211 us; speedup 1.0000x reference)
//
#include <hip/hip_runtime.h>

#define D_DIM 256
#define K_CODES 1024
#define S_STAGES 4
#define BETA 0.25f
#define DECAY 0.99f
#define EPS_F 1e-5f
#define LDSW 40   // padded row stride (elems) for 32-elem chunks: 80B rows
#define CHUNK 64  // tokens per chunksum block

typedef float f32x4 __attribute__((ext_vector_type(4)));
typedef short s16x8 __attribute__((ext_vector_type(8)));

__device__ __forceinline__ unsigned short f2bf(float f) {
    unsigned u = __float_as_uint(f);
    unsigned r = u + 0x7fffu + ((u >> 16) & 1u);
    return (unsigned short)(r >> 16);
}
__device__ __forceinline__ float bf2f(unsigned short u) {
    return __uint_as_float(((unsigned)u) << 16);
}
__device__ __forceinline__ void split3(float x, unsigned short& h, unsigned short& m, unsigned short& l) {
    h = f2bf(x);
    float r1 = x - bf2f(h);
    m = f2bf(r1);
    float r2 = r1 - bf2f(m);
    l = f2bf(r2);
}
// packed 2xf32 -> 2xbf16 in one instr (gfx950)
__device__ __forceinline__ unsigned cvt_pk_bf16(float lo, float hi) {
    unsigned r;
    asm("v_cvt_pk_bf16_f32 %0, %1, %2" : "=v"(r) : "v"(lo), "v"(hi));
    return r;
}

// ---------- sum of squares per code row (numpy pairwise order) ----------
__global__ void k_sumsq(const float* __restrict__ cb, float* __restrict__ out) {
    #pragma clang fp contract(off)
    int i = blockIdx.x * blockDim.x + threadIdx.x;
    if (i >= S_STAGES * K_CODES) return;
    const float* p = cb + (size_t)i * D_DIM;
    float tot = 0.0f;
    for (int h = 0; h < 256; h += 128) {
        const float* q = p + h;
        float r[8];
        #pragma unroll
        for (int j = 0; j < 8; ++j) { float v = q[j]; r[j] = v * v; }
        for (int t = 8; t < 128; t += 8) {
            #pragma unroll
            for (int j = 0; j < 8; ++j) { float v = q[t + j]; r[j] = r[j] + v * v; }
        }
        float res = ((r[0] + r[1]) + (r[2] + r[3])) + ((r[4] + r[5]) + (r[6] + r[7]));
        tot = tot + res;
    }
    out[i] = tot;
}

// ---------- precompute codebook 3-term bf16 splits, layout [S][8 dc][K][32] ----------
__global__ void k_splitB(const float* __restrict__ cb,
                         unsigned short* __restrict__ Bh,
                         unsigned short* __restrict__ Bm,
                         unsigned short* __restrict__ Bl) {
    const int TOT = S_STAGES * K_CODES * D_DIM;
    for (int e = blockIdx.x * blockDim.x + threadIdx.x; e < TOT; e += gridDim.x * blockDim.x) {
        int s = e >> 18, k = (e >> 8) & 1023, d = e & 255;
        float x = cb[e];
        unsigned short h, m, l;
        split3(x, h, m, l);
        size_t o = ((((size_t)s * 8 + (d >> 5)) * K_CODES) + k) * 32 + (d & 31);
        Bh[o] = h; Bm[o] = m; Bl[o] = l;
    }
}

// ---------- MFMA argmin: 128 tokens x 1024 codes per block ----------
// A+Bh+Bm via LDS (5 planes, 51.2KB -> 3 blocks/CU); Bl direct global->VGPR.
__global__ __launch_bounds__(256, 3)
void k_argmin_mfma(const float* __restrict__ Rsrc,
                   const unsigned short* __restrict__ Bh,
                   const unsigned short* __restrict__ Bm,
                   const unsigned short* __restrict__ Bl,
                   const float* __restrict__ ss_s,
                   const int sidx,
                   int* __restrict__ idx_int,
                   float* __restrict__ idx_f,
                   int* __restrict__ hist)
{
    __shared__ __align__(16) unsigned short Ap0[128 * LDSW];
    __shared__ __align__(16) unsigned short Ap1[128 * LDSW];
    __shared__ __align__(16) unsigned short Ap2[128 * LDSW];
    __shared__ __align__(16) unsigned short Bp0[128 * LDSW];
    __shared__ __align__(16) unsigned short Bp1[128 * LDSW];
    __shared__ float redD[128];
    __shared__ int   redI[128];

    const int tid = threadIdx.x;
    const int lane = tid & 63, w = tid >> 6;
    const int wr = w >> 1, wc = w & 1;
    const int r15 = lane & 15, g = lane >> 4;
    const int tokbase = blockIdx.x * 128;

    const int arow = tid & 127, ah = tid >> 7;   // A staging: 2 threads/row, 16 floats each
    const int brow = tid >> 1,  bhh = tid & 1;   // B staging: 2 threads/row, 16 bf16 each

    float best[4][4];
    int   besti[4][4];
    #pragma unroll
    for (int mt = 0; mt < 4; ++mt)
        #pragma unroll
        for (int j = 0; j < 4; ++j) { best[mt][j] = 3.4e38f; besti[mt][j] = 0; }

    for (int kt = 0; kt < 8; ++kt) {
        f32x4 acc[4][4];
        #pragma unroll
        for (int mt = 0; mt < 4; ++mt)
            #pragma unroll
            for (int nt = 0; nt < 4; ++nt) acc[mt][nt] = (f32x4){0.f, 0.f, 0.f, 0.f};

        for (int dc = 0; dc < 8; ++dc) {
            const int dbase32 = dc * 32;
            // ---- Bl fragments: direct global load, issued earliest (used in last pass) ----
            const size_t dfrag = (((size_t)sidx * 8 + dc) * K_CODES + kt * 128 + wc * 64) * 32;
            const int fo = r15 * 32 + g * 8;
            s16x8 bl[4];
            #pragma unroll
            for (int nt = 0; nt < 4; ++nt)
                bl[nt] = *(const s16x8*)(Bl + dfrag + nt * 512 + fo);

            // ---- A read + 3-term cvt_pk split in registers (pre-barrier) ----
            const float4* asrc = (const float4*)(Rsrc + (size_t)(tokbase + arow) * D_DIM + dbase32 + ah * 16);
            const float4 t0 = asrc[0], t1 = asrc[1], t2 = asrc[2], t3 = asrc[3];
            float xs[16];
            xs[0]=t0.x; xs[1]=t0.y; xs[2]=t0.z; xs[3]=t0.w;
            xs[4]=t1.x; xs[5]=t1.y; xs[6]=t1.z; xs[7]=t1.w;
            xs[8]=t2.x; xs[9]=t2.y; xs[10]=t2.z; xs[11]=t2.w;
            xs[12]=t3.x; xs[13]=t3.y; xs[14]=t3.z; xs[15]=t3.w;
            unsigned wh[8], wm[8], wl[8];
            #pragma unroll
            for (int j = 0; j < 8; ++j) {
                const float x0 = xs[2*j], x1 = xs[2*j+1];
                const unsigned h = cvt_pk_bf16(x0, x1);
                const float h0 = __uint_as_float(h << 16);
                const float h1 = __uint_as_float(h & 0xffff0000u);
                const float r0 = x0 - h0, r1 = x1 - h1;
                const unsigned m = cvt_pk_bf16(r0, r1);
                const float m0 = __uint_as_float(m << 16);
                const float m1 = __uint_as_float(m & 0xffff0000u);
                const unsigned l = cvt_pk_bf16(r0 - m0, r1 - m1);
                wh[j] = h; wm[j] = m; wl[j] = l;
            }
            // ---- B h/m staging source (pre-barrier issue) ----
            const size_t gbase = ((((size_t)sidx * 8 + dc) * K_CODES) + kt * 128 + brow) * 32 + bhh * 16;
            const uint4 sb0a = *(const uint4*)(Bh + gbase);
            const uint4 sb0b = *(const uint4*)(Bh + gbase + 8);
            const uint4 sb1a = *(const uint4*)(Bm + gbase);
            const uint4 sb1b = *(const uint4*)(Bm + gbase + 8);

            __syncthreads();   // prior MFMA passes done reading LDS
            {
                const int o = arow * LDSW + ah * 16;
                *(uint4*)&Ap0[o]     = (uint4){wh[0], wh[1], wh[2], wh[3]};
                *(uint4*)&Ap0[o + 8] = (uint4){wh[4], wh[5], wh[6], wh[7]};
                *(uint4*)&Ap1[o]     = (uint4){wm[0], wm[1], wm[2], wm[3]};
                *(uint4*)&Ap1[o + 8] = (uint4){wm[4], wm[5], wm[6], wm[7]};
                *(uint4*)&Ap2[o]     = (uint4){wl[0], wl[1], wl[2], wl[3]};
                *(uint4*)&Ap2[o + 8] = (uint4){wl[4], wl[5], wl[6], wl[7]};
                const int ob = brow * LDSW + bhh * 16;
                *(uint4*)&Bp0[ob] = sb0a; *(uint4*)&Bp0[ob + 8] = sb0b;
                *(uint4*)&Bp1[ob] = sb1a; *(uint4*)&Bp1[ob + 8] = sb1b;
            }
            __syncthreads();

            // ---- fragments + 96 MFMA ----
            s16x8 a0[4], a1[4], a2[4], bb[4];
            #pragma unroll
            for (int mt = 0; mt < 4; ++mt) {
                const int o = (wr * 64 + mt * 16 + r15) * LDSW + g * 8;
                a0[mt] = *(const s16x8*)&Ap0[o];
                a1[mt] = *(const s16x8*)&Ap1[o];
                a2[mt] = *(const s16x8*)&Ap2[o];
            }
            // group B=hi: A in {h,m,l}
            #pragma unroll
            for (int nt = 0; nt < 4; ++nt)
                bb[nt] = *(const s16x8*)&Bp0[(wc * 64 + nt * 16 + r15) * LDSW + g * 8];
            #pragma unroll
            for (int mt = 0; mt < 4; ++mt)
                #pragma unroll
                for (int nt = 0; nt < 4; ++nt)
                    acc[mt][nt] = __builtin_amdgcn_mfma_f32_16x16x32_bf16(a0[mt], bb[nt], acc[mt][nt], 0, 0, 0);
            #pragma unroll
            for (int mt = 0; mt < 4; ++mt)
                #pragma unroll
                for (int nt = 0; nt < 4; ++nt)
                    acc[mt][nt] = __builtin_amdgcn_mfma_f32_16x16x32_bf16(a1[mt], bb[nt], acc[mt][nt], 0, 0, 0);
            #pragma unroll
            for (int mt = 0; mt < 4; ++mt)
                #pragma unroll
                for (int nt = 0; nt < 4; ++nt)
                    acc[mt][nt] = __builtin_amdgcn_mfma_f32_16x16x32_bf16(a2[mt], bb[nt], acc[mt][nt], 0, 0, 0);
            // group B=mid: A in {h,m}
            #pragma unroll
            for (int nt = 0; nt < 4; ++nt)
                bb[nt] = *(const s16x8*)&Bp1[(wc * 64 + nt * 16 + r15) * LDSW + g * 8];
            #pragma unroll
            for (int mt = 0; mt < 4; ++mt)
                #pragma unroll
                for (int nt = 0; nt < 4; ++nt)
                    acc[mt][nt] = __builtin_amdgcn_mfma_f32_16x16x32_bf16(a0[mt], bb[nt], acc[mt][nt], 0, 0, 0);
            #pragma unroll
            for (int mt = 0; mt < 4; ++mt)
                #pragma unroll
                for (int nt = 0; nt < 4; ++nt)
                    acc[mt][nt] = __builtin_amdgcn_mfma_f32_16x16x32_bf16(a1[mt], bb[nt], acc[mt][nt], 0, 0, 0);
            // group B=lo (direct regs): A in {h}
            #pragma unroll
            for (int mt = 0; mt < 4; ++mt)
                #pragma unroll
                for (int nt = 0; nt < 4; ++nt)
                    acc[mt][nt] = __builtin_amdgcn_mfma_f32_16x16x32_bf16(a0[mt], bl[nt], acc[mt][nt], 0, 0, 0);
        }

        // ---- epilogue: dist = ss - 2*dot, running first-min (k ascending) ----
        #pragma unroll
        for (int nt = 0; nt < 4; ++nt) {
            const int kcol = kt * 128 + wc * 64 + nt * 16 + r15;
            const float ssv = ss_s[kcol];
            #pragma unroll
            for (int mt = 0; mt < 4; ++mt) {
                #pragma unroll
                for (int j = 0; j < 4; ++j) {
                    const float dist = ssv - 2.0f * acc[mt][nt][j];
                    if (dist < best[mt][j]) { best[mt][j] = dist; besti[mt][j] = kcol; }
                }
            }
        }
    }

    // ---- reduce over the 16 col-lanes within each warp ----
    float rbd[4][4];
    int   rbi[4][4];
    #pragma unroll
    for (int mt = 0; mt < 4; ++mt) {
        #pragma unroll
        for (int j = 0; j < 4; ++j) {
            float bd = best[mt][j];
            int bi = besti[mt][j];
            #pragma unroll
            for (int mm = 1; mm <= 8; mm <<= 1) {
                const float od = __shfl_xor(bd, mm, 64);
                const int oi = __shfl_xor(bi, mm, 64);
                if (od < bd || (od == bd && oi < bi)) { bd = od; bi = oi; }
            }
            rbd[mt][j] = bd; rbi[mt][j] = bi;
        }
    }
    // ---- cross-warp combine: wc==1 deposits, wc==0 merges + writes ----
    __syncthreads();
    #pragma unroll
    for (int mt = 0; mt < 4; ++mt)
        #pragma unroll
        for (int j = 0; j < 4; ++j)
            if (wc == 1 && r15 == 0) {
                const int trow = wr * 64 + mt * 16 + g * 4 + j;
                redD[trow] = rbd[mt][j];
                redI[trow] = rbi[mt][j];
            }
    __syncthreads();
    #pragma unroll
    for (int mt = 0; mt < 4; ++mt)
        #pragma unroll
        for (int j = 0; j < 4; ++j)
            if (wc == 0 && r15 == 0) {
                const int trow = wr * 64 + mt * 16 + g * 4 + j;
                float bd = rbd[mt][j];
                int bi = rbi[mt][j];
                const float od = redD[trow];
                const int oi = redI[trow];
                if (od < bd || (od == bd && oi < bi)) { bd = od; bi = oi; }
                const int n = tokbase + trow;
                idx_int[n] = bi;
                idx_f[n] = (float)bi;
                atomicAdd(&hist[bi], 1);
            }
}

// ---------- prefix sum over 1024 bins (1 block, 256 threads) ----------
__global__ void k_scan(const int* __restrict__ hist, int* __restrict__ off,
                       int* __restrict__ cursor) {
    __shared__ int tsum[256];
    const int t = threadIdx.x;
    int v[4], s = 0;
    #pragma unroll
    for (int j = 0; j < 4; ++j) { v[j] = hist[t * 4 + j]; s += v[j]; }
    tsum[t] = s;
    __syncthreads();
    if (t == 0) {
        int run = 0;
        for (int i = 0; i < 256; ++i) { int x = tsum[i]; tsum[i] = run; run += x; }
    }
    __syncthreads();
    int run = tsum[t];
    #pragma unroll
    for (int j = 0; j < 4; ++j) {
        off[t * 4 + j] = run;
        cursor[t * 4 + j] = run;
        run += v[j];
    }
    if (t == 255) off[K_CODES] = run;
}

// ---------- scatter tokens into per-code lists ----------
__global__ void k_scatter(const int* __restrict__ idx_s, int* __restrict__ cursor,
                          int* __restrict__ perm, const int Nt) {
    for (int n = blockIdx.x * blockDim.x + threadIdx.x; n < Nt; n += gridDim.x * blockDim.x) {
        const int pos = atomicAdd(&cursor[idx_s[n]], 1);
        perm[pos] = n;
    }
}

// ---------- balanced chunked segment sum over sorted tokens ----------
__global__ __launch_bounds__(256) void k_chunksum(const float* __restrict__ Rsrc,
                                                  const int* __restrict__ perm,
                                                  const int* __restrict__ idx_s,
                                                  float* __restrict__ accum) {
    __shared__ int pl[CHUNK];
    __shared__ int kl[CHUNK];
    const int t = threadIdx.x;
    const int base = blockIdx.x * CHUNK;
    if (t < CHUNK) pl[t] = perm[base + t];
    __syncthreads();
    if (t < CHUNK) kl[t] = idx_s[pl[t]];
    __syncthreads();
    float acc = 0.0f;
    int cur = kl[0];
    for (int m = 0; m < CHUNK; ++m) {
        const int k = kl[m];               // wave-uniform
        if (k != cur) {
            atomicAdd(&accum[(size_t)cur * D_DIM + t], acc);
            acc = 0.0f;
            cur = k;
        }
        acc += Rsrc[(size_t)pl[m] * D_DIM + t];
    }
    atomicAdd(&accum[(size_t)cur * D_DIM + t], acc);
}

// ---------- EMA finalize from complete sums + counts ----------
__global__ void k_ema_final(const float* __restrict__ accum,
                            const int* __restrict__ hist,
                            const float* __restrict__ N_in,     // + s*K
                            const float* __restrict__ zavg_in,  // + s*K*D
                            float* __restrict__ out_N,
                            float* __restrict__ out_zavg,
                            float* __restrict__ out_cb) {
    const int k = blockIdx.x, t = threadIdx.x;
    const float cnt = (float)hist[k];
    const float zk = accum[(size_t)k * D_DIM + t] / (cnt + EPS_F);
    const float Ns = DECAY * N_in[k] + (1.0f - DECAY) * cnt;
    const float za = DECAY * zavg_in[(size_t)k * D_DIM + t] + (1.0f - DECAY) * zk;
    out_zavg[(size_t)k * D_DIM + t] = za;
    out_cb[(size_t)k * D_DIM + t] = za / (Ns + EPS_F);
    if (t == 0) out_N[k] = Ns;
}

// ---------- residual update + per-stage loss (mode 1: final stage writes z_q) ----------
__global__ void k_resid(const float* __restrict__ Rsrc, const float* __restrict__ z,
                        const float* __restrict__ cb_s, const int* __restrict__ idx_s,
                        float* __restrict__ Rdst, float* __restrict__ out_zq,
                        float* __restrict__ loss_s, const int mode, const int total4) {
    float lp = 0.0f;
    for (int i = blockIdx.x * blockDim.x + threadIdx.x; i < total4; i += gridDim.x * blockDim.x) {
        const int n = i >> 6;
        const int c = (i & 63) << 2;
        const int k = idx_s[n];
        const float4 r = *(const float4*)(Rsrc + (size_t)n * D_DIM + c);
        const float4 q = *(const float4*)(cb_s + (size_t)k * D_DIM + c);
        const float dx = q.x - r.x, dy = q.y - r.y, dz = q.z - r.z, dw = q.w - r.w;
        lp += dx * dx + dy * dy + dz * dz + dw * dw;
        if (mode == 0) {
            float4 o;
            o.x = r.x - q.x; o.y = r.y - q.y; o.z = r.z - q.z; o.w = r.w - q.w;
            *(float4*)(Rdst + (size_t)n * D_DIM + c) = o;
        } else {
            const float4 zv = *(const float4*)(z + (size_t)n * D_DIM + c);
            float4 o;
            o.x = (zv.x - r.x) + q.x;
            o.y = (zv.y - r.y) + q.y;
            o.z = (zv.z - r.z) + q.z;
            o.w = (zv.w - r.w) + q.w;
            *(float4*)(out_zq + (size_t)n * D_DIM + c) = o;
        }
    }
    #pragma unroll
    for (int offs = 32; offs > 0; offs >>= 1) lp += __shfl_down(lp, offs, 64);
    __shared__ float wsum[4];
    const int lane = threadIdx.x & 63, w = threadIdx.x >> 6;
    if (lane == 0) wsum[w] = lp;
    __syncthreads();
    if (threadIdx.x == 0) atomicAdd(loss_s, (wsum[0] + wsum[1]) + (wsum[2] + wsum[3]));
}

__global__ void k_loss_final(const float* __restrict__ loss_acc,
                             float* __restrict__ out_loss, const float meanDiv) {
    if (threadIdx.x == 0 && blockIdx.x == 0) {
        float loss = 0.0f;
        #pragma unroll
        for (int s = 0; s < S_STAGES; ++s) loss = loss + BETA * (loss_acc[s] / meanDiv);
        out_loss[0] = loss;
    }
}

extern "C" void kernel_launch(void* const* d_in, const int* in_sizes, int n_in,
                              void* d_out, int out_size, void* d_ws, size_t ws_size,
                              hipStream_t stream)
{
    const float* z = (const float*)d_in[0];
    const float* cb = (const float*)d_in[1];
    const float* N_in = (const float*)d_in[2];
    const float* zavg = (const float*)d_in[3];
    float* out = (float*)d_out;

    const int Nt = in_sizes[0] / D_DIM;      // 65536
    const int total4 = Nt * (D_DIM / 4);

    // ---- workspace layout (~75.7 MB) ----
    char* wp = (char*)d_ws;
    int* idx_ws = (int*)wp;                 wp += (size_t)S_STAGES * Nt * 4;
    int* perm   = (int*)wp;                 wp += (size_t)Nt * 4;
    int* hist   = (int*)wp;                 wp += K_CODES * 4;
    int* cursor = (int*)wp;                 wp += K_CODES * 4;
    int* off    = (int*)wp;                 wp += (K_CODES + 8) * 4;
    float* sumsq = (float*)wp;              wp += S_STAGES * K_CODES * 4;
    float* lossa = (float*)wp;              wp += 64;
    float* accum = (float*)wp;              wp += (size_t)K_CODES * D_DIM * 4;
    unsigned short* Bh = (unsigned short*)wp; wp += (size_t)S_STAGES * K_CODES * D_DIM * 2;
    unsigned short* Bm = (unsigned short*)wp; wp += (size_t)S_STAGES * K_CODES * D_DIM * 2;
    unsigned short* Bl = (unsigned short*)wp; wp += (size_t)S_STAGES * K_CODES * D_DIM * 2;
    wp = (char*)(((size_t)wp + 255) & ~(size_t)255);
    float* Rbuf = (float*)wp;               // Nt * D fp32 (64 MB)

    const size_t ZQ_OFF = 0;
    const size_t LOSS_OFF = (size_t)Nt * D_DIM;
    const size_t IDX_OFF = LOSS_OFF + 1;
    const size_t CB_OFF = IDX_OFF + (size_t)S_STAGES * Nt;
    const size_t N_OFF = CB_OFF + (size_t)S_STAGES * K_CODES * D_DIM;
    const size_t ZAVG_OFF = N_OFF + (size_t)S_STAGES * K_CODES;

    hipMemsetAsync(lossa, 0, 64, stream);
    k_sumsq<<<(S_STAGES * K_CODES + 255) / 256, 256, 0, stream>>>(cb, sumsq);
    k_splitB<<<1024, 256, 0, stream>>>(cb, Bh, Bm, Bl);

    for (int s = 0; s < S_STAGES; ++s) {
        const float* Rsrc = (s == 0) ? z : Rbuf;
        int* idx_s = idx_ws + (size_t)s * Nt;
        hipMemsetAsync(hist, 0, K_CODES * 4, stream);
        hipMemsetAsync(accum, 0, (size_t)K_CODES * D_DIM * 4, stream);
        k_argmin_mfma<<<Nt / 128, 256, 0, stream>>>(
            Rsrc, Bh, Bm, Bl, sumsq + s * K_CODES, s,
            idx_s, out + IDX_OFF + (size_t)s * Nt, hist);
        k_scan<<<1, 256, 0, stream>>>(hist, off, cursor);
        k_scatter<<<64, 256, 0, stream>>>(idx_s, cursor, perm, Nt);
        k_chunksum<<<Nt / CHUNK, 256, 0, stream>>>(Rsrc, perm, idx_s, accum);
        k_ema_final<<<K_CODES, 256, 0, stream>>>(
            accum, hist,
            N_in + s * K_CODES, zavg + (size_t)s * K_CODES * D_DIM,
            out + N_OFF + s * K_CODES,
            out + ZAVG_OFF + (size_t)s * K_CODES * D_DIM,
            out + CB_OFF + (size_t)s * K_CODES * D_DIM);
        k_resid<<<2048, 256, 0, stream>>>(
            Rsrc, z, cb + (size_t)s * K_CODES * D_DIM, idx_s,
            Rbuf, out + ZQ_OFF, lossa + s, (s == 3) ? 1 : 0, total4);
    }
    k_loss_final<<<1, 64, 0, stream>>>(lossa, out + LOSS_OFF, (float)((size_t)Nt * D_DIM));
}

// Round 12
// 1246.826 us; speedup vs baseline: 1.0548x; 1.0548x over previous
//
#include <hip/hip_runtime.h>

#define D_DIM 256
#define K_CODES 1024
#define S_STAGES 4
#define BETA 0.25f
#define DECAY 0.99f
#define EPS_F 1e-5f
#define LDSW 40   // padded row stride (elems) for 32-elem chunks: 80B rows
#define CHUNK 64  // tokens per chunksum block

typedef float f32x4 __attribute__((ext_vector_type(4)));
typedef short s16x8 __attribute__((ext_vector_type(8)));

__device__ __forceinline__ unsigned short f2bf(float f) {
    unsigned u = __float_as_uint(f);
    unsigned r = u + 0x7fffu + ((u >> 16) & 1u);
    return (unsigned short)(r >> 16);
}
__device__ __forceinline__ float bf2f(unsigned short u) {
    return __uint_as_float(((unsigned)u) << 16);
}
__device__ __forceinline__ void split3(float x, unsigned short& h, unsigned short& m, unsigned short& l) {
    h = f2bf(x);
    float r1 = x - bf2f(h);
    m = f2bf(r1);
    float r2 = r1 - bf2f(m);
    l = f2bf(r2);
}
// packed 2xf32 -> 2xbf16 in one instr (gfx950)
__device__ __forceinline__ unsigned cvt_pk_bf16(float lo, float hi) {
    unsigned r;
    asm("v_cvt_pk_bf16_f32 %0, %1, %2" : "=v"(r) : "v"(lo), "v"(hi));
    return r;
}

// ---------- sum of squares per code row (numpy pairwise order) ----------
__global__ void k_sumsq(const float* __restrict__ cb, float* __restrict__ out) {
    #pragma clang fp contract(off)
    int i = blockIdx.x * blockDim.x + threadIdx.x;
    if (i >= S_STAGES * K_CODES) return;
    const float* p = cb + (size_t)i * D_DIM;
    float tot = 0.0f;
    for (int h = 0; h < 256; h += 128) {
        const float* q = p + h;
        float r[8];
        #pragma unroll
        for (int j = 0; j < 8; ++j) { float v = q[j]; r[j] = v * v; }
        for (int t = 8; t < 128; t += 8) {
            #pragma unroll
            for (int j = 0; j < 8; ++j) { float v = q[t + j]; r[j] = r[j] + v * v; }
        }
        float res = ((r[0] + r[1]) + (r[2] + r[3])) + ((r[4] + r[5]) + (r[6] + r[7]));
        tot = tot + res;
    }
    out[i] = tot;
}

// ---------- precompute codebook 3-term bf16 splits, layout [S][8 dc][K][32] ----------
__global__ void k_splitB(const float* __restrict__ cb,
                         unsigned short* __restrict__ Bh,
                         unsigned short* __restrict__ Bm,
                         unsigned short* __restrict__ Bl) {
    const int TOT = S_STAGES * K_CODES * D_DIM;
    for (int e = blockIdx.x * blockDim.x + threadIdx.x; e < TOT; e += gridDim.x * blockDim.x) {
        int s = e >> 18, k = (e >> 8) & 1023, d = e & 255;
        float x = cb[e];
        unsigned short h, m, l;
        split3(x, h, m, l);
        size_t o = ((((size_t)s * 8 + (d >> 5)) * K_CODES) + k) * 32 + (d & 31);
        Bh[o] = h; Bm[o] = m; Bl[o] = l;
    }
}

// ---------- MFMA argmin: 128 tokens x 1024 codes per block (r10 + T14 load-early) ----------
__global__ __launch_bounds__(256, 2)
void k_argmin_mfma(const float* __restrict__ Rsrc,
                   const unsigned short* __restrict__ Bh,
                   const unsigned short* __restrict__ Bm,
                   const unsigned short* __restrict__ Bl,
                   const float* __restrict__ ss_s,
                   const int sidx,
                   int* __restrict__ idx_int,
                   float* __restrict__ idx_f,
                   int* __restrict__ hist)
{
    __shared__ __align__(16) unsigned short Ap0[128 * LDSW];
    __shared__ __align__(16) unsigned short Ap1[128 * LDSW];
    __shared__ __align__(16) unsigned short Ap2[128 * LDSW];
    __shared__ __align__(16) unsigned short Bp0[128 * LDSW];
    __shared__ __align__(16) unsigned short Bp1[128 * LDSW];
    __shared__ __align__(16) unsigned short Bp2[128 * LDSW];
    __shared__ float redD[128];
    __shared__ int   redI[128];

    const int tid = threadIdx.x;
    const int lane = tid & 63, w = tid >> 6;
    const int wr = w >> 1, wc = w & 1;
    const int r15 = lane & 15, g = lane >> 4;
    const int tokbase = blockIdx.x * 128;

    const int arow = tid & 127, ah = tid >> 7;   // A staging: 2 threads/row, 16 floats each
    const int brow = tid >> 1,  bhh = tid & 1;   // B staging: 2 threads/row, 16 bf16 each

    float best[4][4];
    int   besti[4][4];
    #pragma unroll
    for (int mt = 0; mt < 4; ++mt)
        #pragma unroll
        for (int j = 0; j < 4; ++j) { best[mt][j] = 3.4e38f; besti[mt][j] = 0; }

    f32x4 acc[4][4];

    // held raw loads for the NEXT iteration (T14: issue-early, use-late)
    float4 rA0, rA1, rA2, rA3;
    uint4 rB0a, rB0b, rB1a, rB1b, rB2a, rB2b;

    #define ISSUE(IT) {                                                                       \
        const int kt_ = (IT) >> 3, dc_ = (IT) & 7;                                            \
        const float4* asrc_ = (const float4*)(Rsrc + (size_t)(tokbase + arow) * D_DIM + dc_ * 32 + ah * 16); \
        rA0 = asrc_[0]; rA1 = asrc_[1]; rA2 = asrc_[2]; rA3 = asrc_[3];                       \
        const size_t gb_ = ((((size_t)sidx * 8 + dc_) * K_CODES) + kt_ * 128 + brow) * 32 + bhh * 16; \
        rB0a = *(const uint4*)(Bh + gb_); rB0b = *(const uint4*)(Bh + gb_ + 8);               \
        rB1a = *(const uint4*)(Bm + gb_); rB1b = *(const uint4*)(Bm + gb_ + 8);               \
        rB2a = *(const uint4*)(Bl + gb_); rB2b = *(const uint4*)(Bl + gb_ + 8);               \
    }

    ISSUE(0);

    #pragma unroll 1
    for (int it = 0; it < 64; ++it) {
        const int kt = it >> 3, dc = it & 7;
        if (dc == 0) {
            #pragma unroll
            for (int mt = 0; mt < 4; ++mt)
                #pragma unroll
                for (int nt = 0; nt < 4; ++nt) acc[mt][nt] = (f32x4){0.f, 0.f, 0.f, 0.f};
        }

        // ---- split held rA (vmcnt long since satisfied by previous MFMA block) ----
        float xs[16];
        xs[0]=rA0.x; xs[1]=rA0.y; xs[2]=rA0.z; xs[3]=rA0.w;
        xs[4]=rA1.x; xs[5]=rA1.y; xs[6]=rA1.z; xs[7]=rA1.w;
        xs[8]=rA2.x; xs[9]=rA2.y; xs[10]=rA2.z; xs[11]=rA2.w;
        xs[12]=rA3.x; xs[13]=rA3.y; xs[14]=rA3.z; xs[15]=rA3.w;
        unsigned wh[8], wm[8], wl[8];
        #pragma unroll
        for (int j = 0; j < 8; ++j) {
            const float x0 = xs[2*j], x1 = xs[2*j+1];
            const unsigned h = cvt_pk_bf16(x0, x1);
            const float h0 = __uint_as_float(h << 16);
            const float h1 = __uint_as_float(h & 0xffff0000u);
            const float r0 = x0 - h0, r1 = x1 - h1;
            const unsigned m = cvt_pk_bf16(r0, r1);
            const float m0 = __uint_as_float(m << 16);
            const float m1 = __uint_as_float(m & 0xffff0000u);
            const unsigned l = cvt_pk_bf16(r0 - m0, r1 - m1);
            wh[j] = h; wm[j] = m; wl[j] = l;
        }

        __syncthreads();   // prior MFMA passes done reading LDS
        {
            const int o = arow * LDSW + ah * 16;
            *(uint4*)&Ap0[o]     = (uint4){wh[0], wh[1], wh[2], wh[3]};
            *(uint4*)&Ap0[o + 8] = (uint4){wh[4], wh[5], wh[6], wh[7]};
            *(uint4*)&Ap1[o]     = (uint4){wm[0], wm[1], wm[2], wm[3]};
            *(uint4*)&Ap1[o + 8] = (uint4){wm[4], wm[5], wm[6], wm[7]};
            *(uint4*)&Ap2[o]     = (uint4){wl[0], wl[1], wl[2], wl[3]};
            *(uint4*)&Ap2[o + 8] = (uint4){wl[4], wl[5], wl[6], wl[7]};
            const int ob = brow * LDSW + bhh * 16;
            *(uint4*)&Bp0[ob] = rB0a; *(uint4*)&Bp0[ob + 8] = rB0b;
            *(uint4*)&Bp1[ob] = rB1a; *(uint4*)&Bp1[ob + 8] = rB1b;
            *(uint4*)&Bp2[ob] = rB2a; *(uint4*)&Bp2[ob + 8] = rB2b;
        }
        __syncthreads();

        // ---- issue NEXT iteration's raw loads; latency hides under the MFMA block ----
        if (it < 63) ISSUE(it + 1);

        // ---- fragments + 96 MFMA (identical to r10) ----
        s16x8 a0[4], a1[4], a2[4], bb[4];
        #pragma unroll
        for (int mt = 0; mt < 4; ++mt) {
            const int o = (wr * 64 + mt * 16 + r15) * LDSW + g * 8;
            a0[mt] = *(const s16x8*)&Ap0[o];
            a1[mt] = *(const s16x8*)&Ap1[o];
            a2[mt] = *(const s16x8*)&Ap2[o];
        }
        // group B=hi: A in {h,m,l}
        #pragma unroll
        for (int nt = 0; nt < 4; ++nt)
            bb[nt] = *(const s16x8*)&Bp0[(wc * 64 + nt * 16 + r15) * LDSW + g * 8];
        #pragma unroll
        for (int mt = 0; mt < 4; ++mt)
            #pragma unroll
            for (int nt = 0; nt < 4; ++nt)
                acc[mt][nt] = __builtin_amdgcn_mfma_f32_16x16x32_bf16(a0[mt], bb[nt], acc[mt][nt], 0, 0, 0);
        #pragma unroll
        for (int mt = 0; mt < 4; ++mt)
            #pragma unroll
            for (int nt = 0; nt < 4; ++nt)
                acc[mt][nt] = __builtin_amdgcn_mfma_f32_16x16x32_bf16(a1[mt], bb[nt], acc[mt][nt], 0, 0, 0);
        #pragma unroll
        for (int mt = 0; mt < 4; ++mt)
            #pragma unroll
            for (int nt = 0; nt < 4; ++nt)
                acc[mt][nt] = __builtin_amdgcn_mfma_f32_16x16x32_bf16(a2[mt], bb[nt], acc[mt][nt], 0, 0, 0);
        // group B=mid: A in {h,m}
        #pragma unroll
        for (int nt = 0; nt < 4; ++nt)
            bb[nt] = *(const s16x8*)&Bp1[(wc * 64 + nt * 16 + r15) * LDSW + g * 8];
        #pragma unroll
        for (int mt = 0; mt < 4; ++mt)
            #pragma unroll
            for (int nt = 0; nt < 4; ++nt)
                acc[mt][nt] = __builtin_amdgcn_mfma_f32_16x16x32_bf16(a0[mt], bb[nt], acc[mt][nt], 0, 0, 0);
        #pragma unroll
        for (int mt = 0; mt < 4; ++mt)
            #pragma unroll
            for (int nt = 0; nt < 4; ++nt)
                acc[mt][nt] = __builtin_amdgcn_mfma_f32_16x16x32_bf16(a1[mt], bb[nt], acc[mt][nt], 0, 0, 0);
        // group B=lo: A in {h}
        #pragma unroll
        for (int nt = 0; nt < 4; ++nt)
            bb[nt] = *(const s16x8*)&Bp2[(wc * 64 + nt * 16 + r15) * LDSW + g * 8];
        #pragma unroll
        for (int mt = 0; mt < 4; ++mt)
            #pragma unroll
            for (int nt = 0; nt < 4; ++nt)
                acc[mt][nt] = __builtin_amdgcn_mfma_f32_16x16x32_bf16(a0[mt], bb[nt], acc[mt][nt], 0, 0, 0);

        // ---- per-kt epilogue: dist = ss - 2*dot, running first-min ----
        if (dc == 7) {
            #pragma unroll
            for (int nt = 0; nt < 4; ++nt) {
                const int kcol = kt * 128 + wc * 64 + nt * 16 + r15;
                const float ssv = ss_s[kcol];
                #pragma unroll
                for (int mt = 0; mt < 4; ++mt) {
                    #pragma unroll
                    for (int j = 0; j < 4; ++j) {
                        const float dist = ssv - 2.0f * acc[mt][nt][j];
                        if (dist < best[mt][j]) { best[mt][j] = dist; besti[mt][j] = kcol; }
                    }
                }
            }
        }
    }
    #undef ISSUE

    // ---- reduce over the 16 col-lanes within each warp ----
    float rbd[4][4];
    int   rbi[4][4];
    #pragma unroll
    for (int mt = 0; mt < 4; ++mt) {
        #pragma unroll
        for (int j = 0; j < 4; ++j) {
            float bd = best[mt][j];
            int bi = besti[mt][j];
            #pragma unroll
            for (int mm = 1; mm <= 8; mm <<= 1) {
                const float od = __shfl_xor(bd, mm, 64);
                const int oi = __shfl_xor(bi, mm, 64);
                if (od < bd || (od == bd && oi < bi)) { bd = od; bi = oi; }
            }
            rbd[mt][j] = bd; rbi[mt][j] = bi;
        }
    }
    // ---- cross-warp combine: wc==1 deposits, wc==0 merges + writes ----
    __syncthreads();
    #pragma unroll
    for (int mt = 0; mt < 4; ++mt)
        #pragma unroll
        for (int j = 0; j < 4; ++j)
            if (wc == 1 && r15 == 0) {
                const int trow = wr * 64 + mt * 16 + g * 4 + j;
                redD[trow] = rbd[mt][j];
                redI[trow] = rbi[mt][j];
            }
    __syncthreads();
    #pragma unroll
    for (int mt = 0; mt < 4; ++mt)
        #pragma unroll
        for (int j = 0; j < 4; ++j)
            if (wc == 0 && r15 == 0) {
                const int trow = wr * 64 + mt * 16 + g * 4 + j;
                float bd = rbd[mt][j];
                int bi = rbi[mt][j];
                const float od = redD[trow];
                const int oi = redI[trow];
                if (od < bd || (od == bd && oi < bi)) { bd = od; bi = oi; }
                const int n = tokbase + trow;
                idx_int[n] = bi;
                idx_f[n] = (float)bi;
                atomicAdd(&hist[bi], 1);
            }
}

// ---------- prefix sum over 1024 bins (1 block, 256 threads) ----------
__global__ void k_scan(const int* __restrict__ hist, int* __restrict__ off,
                       int* __restrict__ cursor) {
    __shared__ int tsum[256];
    const int t = threadIdx.x;
    int v[4], s = 0;
    #pragma unroll
    for (int j = 0; j < 4; ++j) { v[j] = hist[t * 4 + j]; s += v[j]; }
    tsum[t] = s;
    __syncthreads();
    if (t == 0) {
        int run = 0;
        for (int i = 0; i < 256; ++i) { int x = tsum[i]; tsum[i] = run; run += x; }
    }
    __syncthreads();
    int run = tsum[t];
    #pragma unroll
    for (int j = 0; j < 4; ++j) {
        off[t * 4 + j] = run;
        cursor[t * 4 + j] = run;
        run += v[j];
    }
    if (t == 255) off[K_CODES] = run;
}

// ---------- scatter tokens into per-code lists ----------
__global__ void k_scatter(const int* __restrict__ idx_s, int* __restrict__ cursor,
                          int* __restrict__ perm, const int Nt) {
    for (int n = blockIdx.x * blockDim.x + threadIdx.x; n < Nt; n += gridDim.x * blockDim.x) {
        const int pos = atomicAdd(&cursor[idx_s[n]], 1);
        perm[pos] = n;
    }
}

// ---------- balanced chunked segment sum over sorted tokens ----------
__global__ __launch_bounds__(256) void k_chunksum(const float* __restrict__ Rsrc,
                                                  const int* __restrict__ perm,
                                                  const int* __restrict__ idx_s,
                                                  float* __restrict__ accum) {
    __shared__ int pl[CHUNK];
    __shared__ int kl[CHUNK];
    const int t = threadIdx.x;
    const int base = blockIdx.x * CHUNK;
    if (t < CHUNK) pl[t] = perm[base + t];
    __syncthreads();
    if (t < CHUNK) kl[t] = idx_s[pl[t]];
    __syncthreads();
    float acc = 0.0f;
    int cur = kl[0];
    for (int m = 0; m < CHUNK; ++m) {
        const int k = kl[m];               // wave-uniform
        if (k != cur) {
            atomicAdd(&accum[(size_t)cur * D_DIM + t], acc);
            acc = 0.0f;
            cur = k;
        }
        acc += Rsrc[(size_t)pl[m] * D_DIM + t];
    }
    atomicAdd(&accum[(size_t)cur * D_DIM + t], acc);
}

// ---------- EMA finalize from complete sums + counts ----------
__global__ void k_ema_final(const float* __restrict__ accum,
                            const int* __restrict__ hist,
                            const float* __restrict__ N_in,     // + s*K
                            const float* __restrict__ zavg_in,  // + s*K*D
                            float* __restrict__ out_N,
                            float* __restrict__ out_zavg,
                            float* __restrict__ out_cb) {
    const int k = blockIdx.x, t = threadIdx.x;
    const float cnt = (float)hist[k];
    const float zk = accum[(size_t)k * D_DIM + t] / (cnt + EPS_F);
    const float Ns = DECAY * N_in[k] + (1.0f - DECAY) * cnt;
    const float za = DECAY * zavg_in[(size_t)k * D_DIM + t] + (1.0f - DECAY) * zk;
    out_zavg[(size_t)k * D_DIM + t] = za;
    out_cb[(size_t)k * D_DIM + t] = za / (Ns + EPS_F);
    if (t == 0) out_N[k] = Ns;
}

// ---------- residual update + per-stage loss (mode 1: final stage writes z_q) ----------
__global__ void k_resid(const float* __restrict__ Rsrc, const float* __restrict__ z,
                        const float* __restrict__ cb_s, const int* __restrict__ idx_s,
                        float* __restrict__ Rdst, float* __restrict__ out_zq,
                        float* __restrict__ loss_s, const int mode, const int total4) {
    float lp = 0.0f;
    for (int i = blockIdx.x * blockDim.x + threadIdx.x; i < total4; i += gridDim.x * blockDim.x) {
        const int n = i >> 6;
        const int c = (i & 63) << 2;
        const int k = idx_s[n];
        const float4 r = *(const float4*)(Rsrc + (size_t)n * D_DIM + c);
        const float4 q = *(const float4*)(cb_s + (size_t)k * D_DIM + c);
        const float dx = q.x - r.x, dy = q.y - r.y, dz = q.z - r.z, dw = q.w - r.w;
        lp += dx * dx + dy * dy + dz * dz + dw * dw;
        if (mode == 0) {
            float4 o;
            o.x = r.x - q.x; o.y = r.y - q.y; o.z = r.z - q.z; o.w = r.w - q.w;
            *(float4*)(Rdst + (size_t)n * D_DIM + c) = o;
        } else {
            const float4 zv = *(const float4*)(z + (size_t)n * D_DIM + c);
            float4 o;
            o.x = (zv.x - r.x) + q.x;
            o.y = (zv.y - r.y) + q.y;
            o.z = (zv.z - r.z) + q.z;
            o.w = (zv.w - r.w) + q.w;
            *(float4*)(out_zq + (size_t)n * D_DIM + c) = o;
        }
    }
    #pragma unroll
    for (int offs = 32; offs > 0; offs >>= 1) lp += __shfl_down(lp, offs, 64);
    __shared__ float wsum[4];
    const int lane = threadIdx.x & 63, w = threadIdx.x >> 6;
    if (lane == 0) wsum[w] = lp;
    __syncthreads();
    if (threadIdx.x == 0) atomicAdd(loss_s, (wsum[0] + wsum[1]) + (wsum[2] + wsum[3]));
}

__global__ void k_loss_final(const float* __restrict__ loss_acc,
                             float* __restrict__ out_loss, const float meanDiv) {
    if (threadIdx.x == 0 && blockIdx.x == 0) {
        float loss = 0.0f;
        #pragma unroll
        for (int s = 0; s < S_STAGES; ++s) loss = loss + BETA * (loss_acc[s] / meanDiv);
        out_loss[0] = loss;
    }
}

extern "C" void kernel_launch(void* const* d_in, const int* in_sizes, int n_in,
                              void* d_out, int out_size, void* d_ws, size_t ws_size,
                              hipStream_t stream)
{
    const float* z = (const float*)d_in[0];
    const float* cb = (const float*)d_in[1];
    const float* N_in = (const float*)d_in[2];
    const float* zavg = (const float*)d_in[3];
    float* out = (float*)d_out;

    const int Nt = in_sizes[0] / D_DIM;      // 65536
    const int total4 = Nt * (D_DIM / 4);

    // ---- workspace layout (~75.7 MB) ----
    char* wp = (char*)d_ws;
    int* idx_ws = (int*)wp;                 wp += (size_t)S_STAGES * Nt * 4;
    int* perm   = (int*)wp;                 wp += (size_t)Nt * 4;
    int* hist   = (int*)wp;                 wp += K_CODES * 4;
    int* cursor = (int*)wp;                 wp += K_CODES * 4;
    int* off    = (int*)wp;                 wp += (K_CODES + 8) * 4;
    float* sumsq = (float*)wp;              wp += S_STAGES * K_CODES * 4;
    float* lossa = (float*)wp;              wp += 64;
    float* accum = (float*)wp;              wp += (size_t)K_CODES * D_DIM * 4;
    unsigned short* Bh = (unsigned short*)wp; wp += (size_t)S_STAGES * K_CODES * D_DIM * 2;
    unsigned short* Bm = (unsigned short*)wp; wp += (size_t)S_STAGES * K_CODES * D_DIM * 2;
    unsigned short* Bl = (unsigned short*)wp; wp += (size_t)S_STAGES * K_CODES * D_DIM * 2;
    wp = (char*)(((size_t)wp + 255) & ~(size_t)255);
    float* Rbuf = (float*)wp;               // Nt * D fp32 (64 MB)

    const size_t ZQ_OFF = 0;
    const size_t LOSS_OFF = (size_t)Nt * D_DIM;
    const size_t IDX_OFF = LOSS_OFF + 1;
    const size_t CB_OFF = IDX_OFF + (size_t)S_STAGES * Nt;
    const size_t N_OFF = CB_OFF + (size_t)S_STAGES * K_CODES * D_DIM;
    const size_t ZAVG_OFF = N_OFF + (size_t)S_STAGES * K_CODES;

    hipMemsetAsync(lossa, 0, 64, stream);
    k_sumsq<<<(S_STAGES * K_CODES + 255) / 256, 256, 0, stream>>>(cb, sumsq);
    k_splitB<<<1024, 256, 0, stream>>>(cb, Bh, Bm, Bl);

    for (int s = 0; s < S_STAGES; ++s) {
        const float* Rsrc = (s == 0) ? z : Rbuf;
        int* idx_s = idx_ws + (size_t)s * Nt;
        hipMemsetAsync(hist, 0, K_CODES * 4, stream);
        hipMemsetAsync(accum, 0, (size_t)K_CODES * D_DIM * 4, stream);
        k_argmin_mfma<<<Nt / 128, 256, 0, stream>>>(
            Rsrc, Bh, Bm, Bl, sumsq + s * K_CODES, s,
            idx_s, out + IDX_OFF + (size_t)s * Nt, hist);
        k_scan<<<1, 256, 0, stream>>>(hist, off, cursor);
        k_scatter<<<64, 256, 0, stream>>>(idx_s, cursor, perm, Nt);
        k_chunksum<<<Nt / CHUNK, 256, 0, stream>>>(Rsrc, perm, idx_s, accum);
        k_ema_final<<<K_CODES, 256, 0, stream>>>(
            accum, hist,
            N_in + s * K_CODES, zavg + (size_t)s * K_CODES * D_DIM,
            out + N_OFF + s * K_CODES,
            out + ZAVG_OFF + (size_t)s * K_CODES * D_DIM,
            out + CB_OFF + (size_t)s * K_CODES * D_DIM);
        k_resid<<<2048, 256, 0, stream>>>(
            Rsrc, z, cb + (size_t)s * K_CODES * D_DIM, idx_s,
            Rbuf, out + ZQ_OFF, lossa + s, (s == 3) ? 1 : 0, total4);
    }
    k_loss_final<<<1, 64, 0, stream>>>(lossa, out + LOSS_OFF, (float)((size_t)Nt * D_DIM));
}

// Round 13
// 1222.482 us; speedup vs baseline: 1.0759x; 1.0199x over previous
//
#include <hip/hip_runtime.h>

#define D_DIM 256
#define K_CODES 1024
#define S_STAGES 4
#define BETA 0.25f
#define DECAY 0.99f
#define EPS_F 1e-5f
#define LDSW 40   // padded row stride (elems) for 32-elem chunks: 80B rows
#define CHUNK 64  // tokens per chunksum block

typedef float f32x4 __attribute__((ext_vector_type(4)));
typedef short s16x8 __attribute__((ext_vector_type(8)));

__device__ __forceinline__ unsigned short f2bf(float f) {
    unsigned u = __float_as_uint(f);
    unsigned r = u + 0x7fffu + ((u >> 16) & 1u);
    return (unsigned short)(r >> 16);
}
__device__ __forceinline__ float bf2f(unsigned short u) {
    return __uint_as_float(((unsigned)u) << 16);
}
__device__ __forceinline__ void split3(float x, unsigned short& h, unsigned short& m, unsigned short& l) {
    h = f2bf(x);
    float r1 = x - bf2f(h);
    m = f2bf(r1);
    float r2 = r1 - bf2f(m);
    l = f2bf(r2);
}
// packed 2xf32 -> 2xbf16 in one instr (gfx950)
__device__ __forceinline__ unsigned cvt_pk_bf16(float lo, float hi) {
    unsigned r;
    asm("v_cvt_pk_bf16_f32 %0, %1, %2" : "=v"(r) : "v"(lo), "v"(hi));
    return r;
}

// ---------- sum of squares per code row (numpy pairwise order) ----------
__global__ void k_sumsq(const float* __restrict__ cb, float* __restrict__ out) {
    #pragma clang fp contract(off)
    int i = blockIdx.x * blockDim.x + threadIdx.x;
    if (i >= S_STAGES * K_CODES) return;
    const float* p = cb + (size_t)i * D_DIM;
    float tot = 0.0f;
    for (int h = 0; h < 256; h += 128) {
        const float* q = p + h;
        float r[8];
        #pragma unroll
        for (int j = 0; j < 8; ++j) { float v = q[j]; r[j] = v * v; }
        for (int t = 8; t < 128; t += 8) {
            #pragma unroll
            for (int j = 0; j < 8; ++j) { float v = q[t + j]; r[j] = r[j] + v * v; }
        }
        float res = ((r[0] + r[1]) + (r[2] + r[3])) + ((r[4] + r[5]) + (r[6] + r[7]));
        tot = tot + res;
    }
    out[i] = tot;
}

// ---------- precompute codebook 3-term bf16 splits, layout [S][8 dc][K][32] ----------
__global__ void k_splitB(const float* __restrict__ cb,
                         unsigned short* __restrict__ Bh,
                         unsigned short* __restrict__ Bm,
                         unsigned short* __restrict__ Bl) {
    const int TOT = S_STAGES * K_CODES * D_DIM;
    for (int e = blockIdx.x * blockDim.x + threadIdx.x; e < TOT; e += gridDim.x * blockDim.x) {
        int s = e >> 18, k = (e >> 8) & 1023, d = e & 255;
        float x = cb[e];
        unsigned short h, m, l;
        split3(x, h, m, l);
        size_t o = ((((size_t)s * 8 + (d >> 5)) * K_CODES) + k) * 32 + (d & 31);
        Bh[o] = h; Bm[o] = m; Bl[o] = l;
    }
}

// ---------- MFMA argmin + fused residual-update/loss: 128 tokens x 1024 codes ----------
__global__ __launch_bounds__(256, 2)
void k_argmin_mfma(const float* __restrict__ Rsrc,
                   const float* __restrict__ z,
                   const float* __restrict__ cb_s,
                   const unsigned short* __restrict__ Bh,
                   const unsigned short* __restrict__ Bm,
                   const unsigned short* __restrict__ Bl,
                   const float* __restrict__ ss_s,
                   const int sidx,
                   int* __restrict__ idx_int,
                   float* __restrict__ idx_f,
                   int* __restrict__ hist,
                   float* __restrict__ Rbuf,
                   float* __restrict__ zq,
                   float* __restrict__ loss_s,
                   const int mode)
{
    __shared__ __align__(16) unsigned short Ap0[128 * LDSW];
    __shared__ __align__(16) unsigned short Ap1[128 * LDSW];
    __shared__ __align__(16) unsigned short Ap2[128 * LDSW];
    __shared__ __align__(16) unsigned short Bp0[128 * LDSW];
    __shared__ __align__(16) unsigned short Bp1[128 * LDSW];
    __shared__ __align__(16) unsigned short Bp2[128 * LDSW];
    __shared__ float redD[128];
    __shared__ int   redI[128];

    const int tid = threadIdx.x;
    const int lane = tid & 63, w = tid >> 6;
    const int wr = w >> 1, wc = w & 1;
    const int r15 = lane & 15, g = lane >> 4;
    const int tokbase = blockIdx.x * 128;

    const int arow = tid & 127, ah = tid >> 7;   // A staging: 2 threads/row, 16 floats each
    const int brow = tid >> 1,  bhh = tid & 1;   // B staging: 2 threads/row, 16 bf16 each

    float best[4][4];
    int   besti[4][4];
    #pragma unroll
    for (int mt = 0; mt < 4; ++mt)
        #pragma unroll
        for (int j = 0; j < 4; ++j) { best[mt][j] = 3.4e38f; besti[mt][j] = 0; }

    f32x4 acc[4][4];

    // held raw loads for the NEXT iteration (T14: issue-early, use-late)
    float4 rA0, rA1, rA2, rA3;
    uint4 rB0a, rB0b, rB1a, rB1b, rB2a, rB2b;

    #define ISSUE(IT) {                                                                       \
        const int kt_ = (IT) >> 3, dc_ = (IT) & 7;                                            \
        const float4* asrc_ = (const float4*)(Rsrc + (size_t)(tokbase + arow) * D_DIM + dc_ * 32 + ah * 16); \
        rA0 = asrc_[0]; rA1 = asrc_[1]; rA2 = asrc_[2]; rA3 = asrc_[3];                       \
        const size_t gb_ = ((((size_t)sidx * 8 + dc_) * K_CODES) + kt_ * 128 + brow) * 32 + bhh * 16; \
        rB0a = *(const uint4*)(Bh + gb_); rB0b = *(const uint4*)(Bh + gb_ + 8);               \
        rB1a = *(const uint4*)(Bm + gb_); rB1b = *(const uint4*)(Bm + gb_ + 8);               \
        rB2a = *(const uint4*)(Bl + gb_); rB2b = *(const uint4*)(Bl + gb_ + 8);               \
    }

    ISSUE(0);

    #pragma unroll 1
    for (int it = 0; it < 64; ++it) {
        const int kt = it >> 3, dc = it & 7;
        if (dc == 0) {
            #pragma unroll
            for (int mt = 0; mt < 4; ++mt)
                #pragma unroll
                for (int nt = 0; nt < 4; ++nt) acc[mt][nt] = (f32x4){0.f, 0.f, 0.f, 0.f};
        }

        // ---- split held rA (vmcnt satisfied by previous MFMA block) ----
        float xs[16];
        xs[0]=rA0.x; xs[1]=rA0.y; xs[2]=rA0.z; xs[3]=rA0.w;
        xs[4]=rA1.x; xs[5]=rA1.y; xs[6]=rA1.z; xs[7]=rA1.w;
        xs[8]=rA2.x; xs[9]=rA2.y; xs[10]=rA2.z; xs[11]=rA2.w;
        xs[12]=rA3.x; xs[13]=rA3.y; xs[14]=rA3.z; xs[15]=rA3.w;
        unsigned wh[8], wm[8], wl[8];
        #pragma unroll
        for (int j = 0; j < 8; ++j) {
            const float x0 = xs[2*j], x1 = xs[2*j+1];
            const unsigned h = cvt_pk_bf16(x0, x1);
            const float h0 = __uint_as_float(h << 16);
            const float h1 = __uint_as_float(h & 0xffff0000u);
            const float r0 = x0 - h0, r1 = x1 - h1;
            const unsigned m = cvt_pk_bf16(r0, r1);
            const float m0 = __uint_as_float(m << 16);
            const float m1 = __uint_as_float(m & 0xffff0000u);
            const unsigned l = cvt_pk_bf16(r0 - m0, r1 - m1);
            wh[j] = h; wm[j] = m; wl[j] = l;
        }

        __syncthreads();   // prior MFMA passes done reading LDS
        {
            const int o = arow * LDSW + ah * 16;
            *(uint4*)&Ap0[o]     = (uint4){wh[0], wh[1], wh[2], wh[3]};
            *(uint4*)&Ap0[o + 8] = (uint4){wh[4], wh[5], wh[6], wh[7]};
            *(uint4*)&Ap1[o]     = (uint4){wm[0], wm[1], wm[2], wm[3]};
            *(uint4*)&Ap1[o + 8] = (uint4){wm[4], wm[5], wm[6], wm[7]};
            *(uint4*)&Ap2[o]     = (uint4){wl[0], wl[1], wl[2], wl[3]};
            *(uint4*)&Ap2[o + 8] = (uint4){wl[4], wl[5], wl[6], wl[7]};
            const int ob = brow * LDSW + bhh * 16;
            *(uint4*)&Bp0[ob] = rB0a; *(uint4*)&Bp0[ob + 8] = rB0b;
            *(uint4*)&Bp1[ob] = rB1a; *(uint4*)&Bp1[ob + 8] = rB1b;
            *(uint4*)&Bp2[ob] = rB2a; *(uint4*)&Bp2[ob + 8] = rB2b;
        }
        __syncthreads();

        // ---- issue NEXT iteration's raw loads; latency hides under the MFMA block ----
        if (it < 63) ISSUE(it + 1);

        // ---- fragments + 96 MFMA ----
        s16x8 a0[4], a1[4], a2[4], bb[4];
        #pragma unroll
        for (int mt = 0; mt < 4; ++mt) {
            const int o = (wr * 64 + mt * 16 + r15) * LDSW + g * 8;
            a0[mt] = *(const s16x8*)&Ap0[o];
            a1[mt] = *(const s16x8*)&Ap1[o];
            a2[mt] = *(const s16x8*)&Ap2[o];
        }
        // group B=hi: A in {h,m,l}
        #pragma unroll
        for (int nt = 0; nt < 4; ++nt)
            bb[nt] = *(const s16x8*)&Bp0[(wc * 64 + nt * 16 + r15) * LDSW + g * 8];
        #pragma unroll
        for (int mt = 0; mt < 4; ++mt)
            #pragma unroll
            for (int nt = 0; nt < 4; ++nt)
                acc[mt][nt] = __builtin_amdgcn_mfma_f32_16x16x32_bf16(a0[mt], bb[nt], acc[mt][nt], 0, 0, 0);
        #pragma unroll
        for (int mt = 0; mt < 4; ++mt)
            #pragma unroll
            for (int nt = 0; nt < 4; ++nt)
                acc[mt][nt] = __builtin_amdgcn_mfma_f32_16x16x32_bf16(a1[mt], bb[nt], acc[mt][nt], 0, 0, 0);
        #pragma unroll
        for (int mt = 0; mt < 4; ++mt)
            #pragma unroll
            for (int nt = 0; nt < 4; ++nt)
                acc[mt][nt] = __builtin_amdgcn_mfma_f32_16x16x32_bf16(a2[mt], bb[nt], acc[mt][nt], 0, 0, 0);
        // group B=mid: A in {h,m}
        #pragma unroll
        for (int nt = 0; nt < 4; ++nt)
            bb[nt] = *(const s16x8*)&Bp1[(wc * 64 + nt * 16 + r15) * LDSW + g * 8];
        #pragma unroll
        for (int mt = 0; mt < 4; ++mt)
            #pragma unroll
            for (int nt = 0; nt < 4; ++nt)
                acc[mt][nt] = __builtin_amdgcn_mfma_f32_16x16x32_bf16(a0[mt], bb[nt], acc[mt][nt], 0, 0, 0);
        #pragma unroll
        for (int mt = 0; mt < 4; ++mt)
            #pragma unroll
            for (int nt = 0; nt < 4; ++nt)
                acc[mt][nt] = __builtin_amdgcn_mfma_f32_16x16x32_bf16(a1[mt], bb[nt], acc[mt][nt], 0, 0, 0);
        // group B=lo: A in {h}
        #pragma unroll
        for (int nt = 0; nt < 4; ++nt)
            bb[nt] = *(const s16x8*)&Bp2[(wc * 64 + nt * 16 + r15) * LDSW + g * 8];
        #pragma unroll
        for (int mt = 0; mt < 4; ++mt)
            #pragma unroll
            for (int nt = 0; nt < 4; ++nt)
                acc[mt][nt] = __builtin_amdgcn_mfma_f32_16x16x32_bf16(a0[mt], bb[nt], acc[mt][nt], 0, 0, 0);

        // ---- per-kt epilogue: dist = ss - 2*dot, running first-min ----
        if (dc == 7) {
            #pragma unroll
            for (int nt = 0; nt < 4; ++nt) {
                const int kcol = kt * 128 + wc * 64 + nt * 16 + r15;
                const float ssv = ss_s[kcol];
                #pragma unroll
                for (int mt = 0; mt < 4; ++mt) {
                    #pragma unroll
                    for (int j = 0; j < 4; ++j) {
                        const float dist = ssv - 2.0f * acc[mt][nt][j];
                        if (dist < best[mt][j]) { best[mt][j] = dist; besti[mt][j] = kcol; }
                    }
                }
            }
        }
    }
    #undef ISSUE

    // ---- reduce over the 16 col-lanes within each warp ----
    float rbd[4][4];
    int   rbi[4][4];
    #pragma unroll
    for (int mt = 0; mt < 4; ++mt) {
        #pragma unroll
        for (int j = 0; j < 4; ++j) {
            float bd = best[mt][j];
            int bi = besti[mt][j];
            #pragma unroll
            for (int mm = 1; mm <= 8; mm <<= 1) {
                const float od = __shfl_xor(bd, mm, 64);
                const int oi = __shfl_xor(bi, mm, 64);
                if (od < bd || (od == bd && oi < bi)) { bd = od; bi = oi; }
            }
            rbd[mt][j] = bd; rbi[mt][j] = bi;
        }
    }
    // ---- cross-warp combine: wc==1 deposits, wc==0 merges + writes + publishes ----
    __syncthreads();
    #pragma unroll
    for (int mt = 0; mt < 4; ++mt)
        #pragma unroll
        for (int j = 0; j < 4; ++j)
            if (wc == 1 && r15 == 0) {
                const int trow = wr * 64 + mt * 16 + g * 4 + j;
                redD[trow] = rbd[mt][j];
                redI[trow] = rbi[mt][j];
            }
    __syncthreads();
    #pragma unroll
    for (int mt = 0; mt < 4; ++mt)
        #pragma unroll
        for (int j = 0; j < 4; ++j)
            if (wc == 0 && r15 == 0) {
                const int trow = wr * 64 + mt * 16 + g * 4 + j;
                float bd = rbd[mt][j];
                int bi = rbi[mt][j];
                const float od = redD[trow];
                const int oi = redI[trow];
                if (od < bd || (od == bd && oi < bi)) { bd = od; bi = oi; }
                const int n = tokbase + trow;
                idx_int[n] = bi;
                idx_f[n] = (float)bi;
                atomicAdd(&hist[bi], 1);
                redI[trow] = bi;      // publish merged idx for resid epilogue
            }
    __syncthreads();

    // ---- fused residual update + loss (2 threads/row, 128 f32 each) ----
    {
        const int n = tokbase + arow;
        const int kk = redI[arow];
        const float4* rs = (const float4*)(Rsrc + (size_t)n * D_DIM + ah * 128);
        const float4* qs = (const float4*)(cb_s + (size_t)kk * D_DIM + ah * 128);
        float4* rd = (float4*)(Rbuf + (size_t)n * D_DIM + ah * 128);
        float lp = 0.0f;
        if (mode == 0) {
            #pragma unroll 4
            for (int j = 0; j < 32; ++j) {
                const float4 r4 = rs[j];
                const float4 q4 = qs[j];
                float4 o;
                o.x = r4.x - q4.x; o.y = r4.y - q4.y;
                o.z = r4.z - q4.z; o.w = r4.w - q4.w;
                lp += o.x * o.x + o.y * o.y + o.z * o.z + o.w * o.w;
                rd[j] = o;
            }
        } else {
            const float4* zs = (const float4*)(z + (size_t)n * D_DIM + ah * 128);
            float4* os = (float4*)(zq + (size_t)n * D_DIM + ah * 128);
            #pragma unroll 4
            for (int j = 0; j < 32; ++j) {
                const float4 r4 = rs[j];
                const float4 q4 = qs[j];
                const float4 z4 = zs[j];
                float4 o;
                o.x = r4.x - q4.x; o.y = r4.y - q4.y;
                o.z = r4.z - q4.z; o.w = r4.w - q4.w;
                lp += o.x * o.x + o.y * o.y + o.z * o.z + o.w * o.w;
                rd[j] = o;
                float4 zo;
                zo.x = z4.x - o.x; zo.y = z4.y - o.y;
                zo.z = z4.z - o.z; zo.w = z4.w - o.w;
                os[j] = zo;
            }
        }
        #pragma unroll
        for (int off = 32; off > 0; off >>= 1) lp += __shfl_down(lp, off, 64);
        if (lane == 0) redD[w] = lp;
        __syncthreads();
        if (tid == 0) atomicAdd(loss_s, (redD[0] + redD[1]) + (redD[2] + redD[3]));
    }
}

// ---------- prefix sum over 1024 bins (1 block, 256 threads) ----------
__global__ void k_scan(const int* __restrict__ hist, int* __restrict__ off,
                       int* __restrict__ cursor) {
    __shared__ int tsum[256];
    const int t = threadIdx.x;
    int v[4], s = 0;
    #pragma unroll
    for (int j = 0; j < 4; ++j) { v[j] = hist[t * 4 + j]; s += v[j]; }
    tsum[t] = s;
    __syncthreads();
    if (t == 0) {
        int run = 0;
        for (int i = 0; i < 256; ++i) { int x = tsum[i]; tsum[i] = run; run += x; }
    }
    __syncthreads();
    int run = tsum[t];
    #pragma unroll
    for (int j = 0; j < 4; ++j) {
        off[t * 4 + j] = run;
        cursor[t * 4 + j] = run;
        run += v[j];
    }
    if (t == 255) off[K_CODES] = run;
}

// ---------- scatter tokens into per-code lists ----------
__global__ void k_scatter(const int* __restrict__ idx_s, int* __restrict__ cursor,
                          int* __restrict__ perm, const int Nt) {
    for (int n = blockIdx.x * blockDim.x + threadIdx.x; n < Nt; n += gridDim.x * blockDim.x) {
        const int pos = atomicAdd(&cursor[idx_s[n]], 1);
        perm[pos] = n;
    }
}

// ---------- balanced chunked segment sum over sorted tokens (post-sub residuals) ----------
__global__ __launch_bounds__(256) void k_chunksum(const float* __restrict__ Rnew,
                                                  const int* __restrict__ perm,
                                                  const int* __restrict__ idx_s,
                                                  float* __restrict__ accum) {
    __shared__ int pl[CHUNK];
    __shared__ int kl[CHUNK];
    const int t = threadIdx.x;
    const int base = blockIdx.x * CHUNK;
    if (t < CHUNK) pl[t] = perm[base + t];
    __syncthreads();
    if (t < CHUNK) kl[t] = idx_s[pl[t]];
    __syncthreads();
    float acc = 0.0f;
    int cur = kl[0];
    for (int m = 0; m < CHUNK; ++m) {
        const int k = kl[m];               // wave-uniform
        if (k != cur) {
            atomicAdd(&accum[(size_t)cur * D_DIM + t], acc);
            acc = 0.0f;
            cur = k;
        }
        acc += Rnew[(size_t)pl[m] * D_DIM + t];
    }
    atomicAdd(&accum[(size_t)cur * D_DIM + t], acc);
}

// ---------- EMA finalize: compensate post-sub sums (pre = post + cnt*cb) ----------
__global__ void k_ema_final(const float* __restrict__ accum,
                            const int* __restrict__ hist,
                            const float* __restrict__ cb_s,
                            const float* __restrict__ N_in,     // + s*K
                            const float* __restrict__ zavg_in,  // + s*K*D
                            float* __restrict__ out_N,
                            float* __restrict__ out_zavg,
                            float* __restrict__ out_cb) {
    const int k = blockIdx.x, t = threadIdx.x;
    const float cnt = (float)hist[k];
    const float presum = accum[(size_t)k * D_DIM + t] + cnt * cb_s[(size_t)k * D_DIM + t];
    const float zk = presum / (cnt + EPS_F);
    const float Ns = DECAY * N_in[k] + (1.0f - DECAY) * cnt;
    const float za = DECAY * zavg_in[(size_t)k * D_DIM + t] + (1.0f - DECAY) * zk;
    out_zavg[(size_t)k * D_DIM + t] = za;
    out_cb[(size_t)k * D_DIM + t] = za / (Ns + EPS_F);
    if (t == 0) out_N[k] = Ns;
}

__global__ void k_loss_final(const float* __restrict__ loss_acc,
                             float* __restrict__ out_loss, const float meanDiv) {
    if (threadIdx.x == 0 && blockIdx.x == 0) {
        float loss = 0.0f;
        #pragma unroll
        for (int s = 0; s < S_STAGES; ++s) loss = loss + BETA * (loss_acc[s] / meanDiv);
        out_loss[0] = loss;
    }
}

extern "C" void kernel_launch(void* const* d_in, const int* in_sizes, int n_in,
                              void* d_out, int out_size, void* d_ws, size_t ws_size,
                              hipStream_t stream)
{
    const float* z = (const float*)d_in[0];
    const float* cb = (const float*)d_in[1];
    const float* N_in = (const float*)d_in[2];
    const float* zavg = (const float*)d_in[3];
    float* out = (float*)d_out;

    const int Nt = in_sizes[0] / D_DIM;      // 65536

    // ---- workspace layout (~75.7 MB) ----
    char* wp = (char*)d_ws;
    int* idx_ws = (int*)wp;                 wp += (size_t)S_STAGES * Nt * 4;
    int* perm   = (int*)wp;                 wp += (size_t)Nt * 4;
    int* hist   = (int*)wp;                 wp += K_CODES * 4;
    int* cursor = (int*)wp;                 wp += K_CODES * 4;
    int* off    = (int*)wp;                 wp += (K_CODES + 8) * 4;
    float* sumsq = (float*)wp;              wp += S_STAGES * K_CODES * 4;
    float* lossa = (float*)wp;              wp += 64;
    float* accum = (float*)wp;              wp += (size_t)K_CODES * D_DIM * 4;
    unsigned short* Bh = (unsigned short*)wp; wp += (size_t)S_STAGES * K_CODES * D_DIM * 2;
    unsigned short* Bm = (unsigned short*)wp; wp += (size_t)S_STAGES * K_CODES * D_DIM * 2;
    unsigned short* Bl = (unsigned short*)wp; wp += (size_t)S_STAGES * K_CODES * D_DIM * 2;
    wp = (char*)(((size_t)wp + 255) & ~(size_t)255);
    float* Rbuf = (float*)wp;               // Nt * D fp32 (64 MB)

    const size_t ZQ_OFF = 0;
    const size_t LOSS_OFF = (size_t)Nt * D_DIM;
    const size_t IDX_OFF = LOSS_OFF + 1;
    const size_t CB_OFF = IDX_OFF + (size_t)S_STAGES * Nt;
    const size_t N_OFF = CB_OFF + (size_t)S_STAGES * K_CODES * D_DIM;
    const size_t ZAVG_OFF = N_OFF + (size_t)S_STAGES * K_CODES;

    hipMemsetAsync(lossa, 0, 64, stream);
    k_sumsq<<<(S_STAGES * K_CODES + 255) / 256, 256, 0, stream>>>(cb, sumsq);
    k_splitB<<<1024, 256, 0, stream>>>(cb, Bh, Bm, Bl);

    for (int s = 0; s < S_STAGES; ++s) {
        const float* Rsrc = (s == 0) ? z : Rbuf;
        const float* cb_s = cb + (size_t)s * K_CODES * D_DIM;
        int* idx_s = idx_ws + (size_t)s * Nt;
        hipMemsetAsync(hist, 0, K_CODES * 4, stream);
        hipMemsetAsync(accum, 0, (size_t)K_CODES * D_DIM * 4, stream);
        k_argmin_mfma<<<Nt / 128, 256, 0, stream>>>(
            Rsrc, z, cb_s, Bh, Bm, Bl, sumsq + s * K_CODES, s,
            idx_s, out + IDX_OFF + (size_t)s * Nt, hist,
            Rbuf, out + ZQ_OFF, lossa + s, (s == 3) ? 1 : 0);
        k_scan<<<1, 256, 0, stream>>>(hist, off, cursor);
        k_scatter<<<64, 256, 0, stream>>>(idx_s, cursor, perm, Nt);
        k_chunksum<<<Nt / CHUNK, 256, 0, stream>>>(Rbuf, perm, idx_s, accum);
        k_ema_final<<<K_CODES, 256, 0, stream>>>(
            accum, hist, cb_s,
            N_in + s * K_CODES, zavg + (size_t)s * K_CODES * D_DIM,
            out + N_OFF + s * K_CODES,
            out + ZAVG_OFF + (size_t)s * K_CODES * D_DIM,
            out + CB_OFF + (size_t)s * K_CODES * D_DIM);
    }
    k_loss_final<<<1, 64, 0, stream>>>(lossa, out + LOSS_OFF, (float)((size_t)Nt * D_DIM));
}

// Round 14
// 1193.055 us; speedup vs baseline: 1.1024x; 1.0247x over previous
//
#include <hip/hip_runtime.h>

#define D_DIM 256
#define K_CODES 1024
#define S_STAGES 4
#define BETA 0.25f
#define DECAY 0.99f
#define EPS_F 1e-5f
#define LDSW 40   // padded row stride (elems) for 32-elem chunks: 80B rows
#define CHUNK 64  // tokens per chunksum block

typedef float f32x4 __attribute__((ext_vector_type(4)));
typedef short s16x8 __attribute__((ext_vector_type(8)));

__device__ __forceinline__ unsigned short f2bf(float f) {
    unsigned u = __float_as_uint(f);
    unsigned r = u + 0x7fffu + ((u >> 16) & 1u);
    return (unsigned short)(r >> 16);
}
__device__ __forceinline__ float bf2f(unsigned short u) {
    return __uint_as_float(((unsigned)u) << 16);
}
__device__ __forceinline__ void split3(float x, unsigned short& h, unsigned short& m, unsigned short& l) {
    h = f2bf(x);
    float r1 = x - bf2f(h);
    m = f2bf(r1);
    float r2 = r1 - bf2f(m);
    l = f2bf(r2);
}
// packed 2xf32 -> 2xbf16 in one instr (gfx950)
__device__ __forceinline__ unsigned cvt_pk_bf16(float lo, float hi) {
    unsigned r;
    asm("v_cvt_pk_bf16_f32 %0, %1, %2" : "=v"(r) : "v"(lo), "v"(hi));
    return r;
}

// ---------- sum of squares per code row (numpy pairwise order) ----------
__global__ void k_sumsq(const float* __restrict__ cb, float* __restrict__ out) {
    #pragma clang fp contract(off)
    int i = blockIdx.x * blockDim.x + threadIdx.x;
    if (i >= S_STAGES * K_CODES) return;
    const float* p = cb + (size_t)i * D_DIM;
    float tot = 0.0f;
    for (int h = 0; h < 256; h += 128) {
        const float* q = p + h;
        float r[8];
        #pragma unroll
        for (int j = 0; j < 8; ++j) { float v = q[j]; r[j] = v * v; }
        for (int t = 8; t < 128; t += 8) {
            #pragma unroll
            for (int j = 0; j < 8; ++j) { float v = q[t + j]; r[j] = r[j] + v * v; }
        }
        float res = ((r[0] + r[1]) + (r[2] + r[3])) + ((r[4] + r[5]) + (r[6] + r[7]));
        tot = tot + res;
    }
    out[i] = tot;
}

// ---------- precompute codebook 3-term bf16 splits, layout [S][8 dc][K][32] ----------
__global__ void k_splitB(const float* __restrict__ cb,
                         unsigned short* __restrict__ Bh,
                         unsigned short* __restrict__ Bm,
                         unsigned short* __restrict__ Bl) {
    const int TOT = S_STAGES * K_CODES * D_DIM;
    for (int e = blockIdx.x * blockDim.x + threadIdx.x; e < TOT; e += gridDim.x * blockDim.x) {
        int s = e >> 18, k = (e >> 8) & 1023, d = e & 255;
        float x = cb[e];
        unsigned short h, m, l;
        split3(x, h, m, l);
        size_t o = ((((size_t)s * 8 + (d >> 5)) * K_CODES) + k) * 32 + (d & 31);
        Bh[o] = h; Bm[o] = m; Bl[o] = l;
    }
}

// ---------- MFMA argmin + fused residual-update/loss: 128 tokens x 1024 codes ----------
__global__ __launch_bounds__(256, 2)
void k_argmin_mfma(const float* __restrict__ Rsrc,
                   const float* __restrict__ z,
                   const float* __restrict__ cb_s,
                   const unsigned short* __restrict__ Bh,
                   const unsigned short* __restrict__ Bm,
                   const unsigned short* __restrict__ Bl,
                   const float* __restrict__ ss_s,
                   const int sidx,
                   int* __restrict__ idx_int,
                   float* __restrict__ idx_f,
                   int* __restrict__ hist,
                   float* __restrict__ Rbuf,
                   float* __restrict__ zq,
                   float* __restrict__ loss_s,
                   const int mode)
{
    __shared__ __align__(16) unsigned short Ap0[128 * LDSW];
    __shared__ __align__(16) unsigned short Ap1[128 * LDSW];
    __shared__ __align__(16) unsigned short Ap2[128 * LDSW];
    __shared__ __align__(16) unsigned short Bp0[128 * LDSW];
    __shared__ __align__(16) unsigned short Bp1[128 * LDSW];
    __shared__ __align__(16) unsigned short Bp2[128 * LDSW];
    __shared__ float redD[128];
    __shared__ int   redI[128];

    const int tid = threadIdx.x;
    const int lane = tid & 63, w = tid >> 6;
    const int wr = w >> 1, wc = w & 1;
    const int r15 = lane & 15, g = lane >> 4;
    const int tokbase = blockIdx.x * 128;

    const int arow = tid & 127, ah = tid >> 7;   // A staging: 2 threads/row, 16 floats each
    const int brow = tid >> 1,  bhh = tid & 1;   // B staging: 2 threads/row, 16 bf16 each

    float best[4][4];
    int   besti[4][4];
    #pragma unroll
    for (int mt = 0; mt < 4; ++mt)
        #pragma unroll
        for (int j = 0; j < 4; ++j) { best[mt][j] = 3.4e38f; besti[mt][j] = 0; }

    f32x4 acc[4][4];

    // held raw loads for the NEXT iteration (T14: issue-early, use-late)
    float4 rA0, rA1, rA2, rA3;
    uint4 rB0a, rB0b, rB1a, rB1b, rB2a, rB2b;

    #define ISSUE(IT) {                                                                       \
        const int kt_ = (IT) >> 3, dc_ = (IT) & 7;                                            \
        const float4* asrc_ = (const float4*)(Rsrc + (size_t)(tokbase + arow) * D_DIM + dc_ * 32 + ah * 16); \
        rA0 = asrc_[0]; rA1 = asrc_[1]; rA2 = asrc_[2]; rA3 = asrc_[3];                       \
        const size_t gb_ = ((((size_t)sidx * 8 + dc_) * K_CODES) + kt_ * 128 + brow) * 32 + bhh * 16; \
        rB0a = *(const uint4*)(Bh + gb_); rB0b = *(const uint4*)(Bh + gb_ + 8);               \
        rB1a = *(const uint4*)(Bm + gb_); rB1b = *(const uint4*)(Bm + gb_ + 8);               \
        rB2a = *(const uint4*)(Bl + gb_); rB2b = *(const uint4*)(Bl + gb_ + 8);               \
    }

    ISSUE(0);

    #pragma unroll 1
    for (int it = 0; it < 64; ++it) {
        const int kt = it >> 3, dc = it & 7;
        if (dc == 0) {
            #pragma unroll
            for (int mt = 0; mt < 4; ++mt)
                #pragma unroll
                for (int nt = 0; nt < 4; ++nt) acc[mt][nt] = (f32x4){0.f, 0.f, 0.f, 0.f};
        }

        // ---- split held rA (vmcnt satisfied by previous MFMA block) ----
        float xs[16];
        xs[0]=rA0.x; xs[1]=rA0.y; xs[2]=rA0.z; xs[3]=rA0.w;
        xs[4]=rA1.x; xs[5]=rA1.y; xs[6]=rA1.z; xs[7]=rA1.w;
        xs[8]=rA2.x; xs[9]=rA2.y; xs[10]=rA2.z; xs[11]=rA2.w;
        xs[12]=rA3.x; xs[13]=rA3.y; xs[14]=rA3.z; xs[15]=rA3.w;
        unsigned wh[8], wm[8], wl[8];
        #pragma unroll
        for (int j = 0; j < 8; ++j) {
            const float x0 = xs[2*j], x1 = xs[2*j+1];
            const unsigned h = cvt_pk_bf16(x0, x1);
            const float h0 = __uint_as_float(h << 16);
            const float h1 = __uint_as_float(h & 0xffff0000u);
            const float r0 = x0 - h0, r1 = x1 - h1;
            const unsigned m = cvt_pk_bf16(r0, r1);
            const float m0 = __uint_as_float(m << 16);
            const float m1 = __uint_as_float(m & 0xffff0000u);
            const unsigned l = cvt_pk_bf16(r0 - m0, r1 - m1);
            wh[j] = h; wm[j] = m; wl[j] = l;
        }

        __syncthreads();   // prior MFMA passes done reading LDS
        {
            const int o = arow * LDSW + ah * 16;
            *(uint4*)&Ap0[o]     = (uint4){wh[0], wh[1], wh[2], wh[3]};
            *(uint4*)&Ap0[o + 8] = (uint4){wh[4], wh[5], wh[6], wh[7]};
            *(uint4*)&Ap1[o]     = (uint4){wm[0], wm[1], wm[2], wm[3]};
            *(uint4*)&Ap1[o + 8] = (uint4){wm[4], wm[5], wm[6], wm[7]};
            *(uint4*)&Ap2[o]     = (uint4){wl[0], wl[1], wl[2], wl[3]};
            *(uint4*)&Ap2[o + 8] = (uint4){wl[4], wl[5], wl[6], wl[7]};
            const int ob = brow * LDSW + bhh * 16;
            *(uint4*)&Bp0[ob] = rB0a; *(uint4*)&Bp0[ob + 8] = rB0b;
            *(uint4*)&Bp1[ob] = rB1a; *(uint4*)&Bp1[ob + 8] = rB1b;
            *(uint4*)&Bp2[ob] = rB2a; *(uint4*)&Bp2[ob + 8] = rB2b;
        }
        __syncthreads();

        // ---- issue NEXT iteration's raw loads; latency hides under the MFMA block ----
        if (it < 63) ISSUE(it + 1);

        // ---- fragments + 96 MFMA (setprio: favor MFMA-cluster wave on the CU) ----
        s16x8 a0[4], a1[4], a2[4], bb[4];
        #pragma unroll
        for (int mt = 0; mt < 4; ++mt) {
            const int o = (wr * 64 + mt * 16 + r15) * LDSW + g * 8;
            a0[mt] = *(const s16x8*)&Ap0[o];
            a1[mt] = *(const s16x8*)&Ap1[o];
            a2[mt] = *(const s16x8*)&Ap2[o];
        }
        __builtin_amdgcn_s_setprio(1);
        // group B=hi: A in {h,m,l}
        #pragma unroll
        for (int nt = 0; nt < 4; ++nt)
            bb[nt] = *(const s16x8*)&Bp0[(wc * 64 + nt * 16 + r15) * LDSW + g * 8];
        #pragma unroll
        for (int mt = 0; mt < 4; ++mt)
            #pragma unroll
            for (int nt = 0; nt < 4; ++nt)
                acc[mt][nt] = __builtin_amdgcn_mfma_f32_16x16x32_bf16(a0[mt], bb[nt], acc[mt][nt], 0, 0, 0);
        #pragma unroll
        for (int mt = 0; mt < 4; ++mt)
            #pragma unroll
            for (int nt = 0; nt < 4; ++nt)
                acc[mt][nt] = __builtin_amdgcn_mfma_f32_16x16x32_bf16(a1[mt], bb[nt], acc[mt][nt], 0, 0, 0);
        #pragma unroll
        for (int mt = 0; mt < 4; ++mt)
            #pragma unroll
            for (int nt = 0; nt < 4; ++nt)
                acc[mt][nt] = __builtin_amdgcn_mfma_f32_16x16x32_bf16(a2[mt], bb[nt], acc[mt][nt], 0, 0, 0);
        // group B=mid: A in {h,m}
        #pragma unroll
        for (int nt = 0; nt < 4; ++nt)
            bb[nt] = *(const s16x8*)&Bp1[(wc * 64 + nt * 16 + r15) * LDSW + g * 8];
        #pragma unroll
        for (int mt = 0; mt < 4; ++mt)
            #pragma unroll
            for (int nt = 0; nt < 4; ++nt)
                acc[mt][nt] = __builtin_amdgcn_mfma_f32_16x16x32_bf16(a0[mt], bb[nt], acc[mt][nt], 0, 0, 0);
        #pragma unroll
        for (int mt = 0; mt < 4; ++mt)
            #pragma unroll
            for (int nt = 0; nt < 4; ++nt)
                acc[mt][nt] = __builtin_amdgcn_mfma_f32_16x16x32_bf16(a1[mt], bb[nt], acc[mt][nt], 0, 0, 0);
        // group B=lo: A in {h}
        #pragma unroll
        for (int nt = 0; nt < 4; ++nt)
            bb[nt] = *(const s16x8*)&Bp2[(wc * 64 + nt * 16 + r15) * LDSW + g * 8];
        #pragma unroll
        for (int mt = 0; mt < 4; ++mt)
            #pragma unroll
            for (int nt = 0; nt < 4; ++nt)
                acc[mt][nt] = __builtin_amdgcn_mfma_f32_16x16x32_bf16(a0[mt], bb[nt], acc[mt][nt], 0, 0, 0);
        __builtin_amdgcn_s_setprio(0);

        // ---- per-kt epilogue: dist = ss - 2*dot, running first-min ----
        if (dc == 7) {
            #pragma unroll
            for (int nt = 0; nt < 4; ++nt) {
                const int kcol = kt * 128 + wc * 64 + nt * 16 + r15;
                const float ssv = ss_s[kcol];
                #pragma unroll
                for (int mt = 0; mt < 4; ++mt) {
                    #pragma unroll
                    for (int j = 0; j < 4; ++j) {
                        const float dist = ssv - 2.0f * acc[mt][nt][j];
                        if (dist < best[mt][j]) { best[mt][j] = dist; besti[mt][j] = kcol; }
                    }
                }
            }
        }
    }
    #undef ISSUE

    // ---- reduce over the 16 col-lanes within each warp ----
    float rbd[4][4];
    int   rbi[4][4];
    #pragma unroll
    for (int mt = 0; mt < 4; ++mt) {
        #pragma unroll
        for (int j = 0; j < 4; ++j) {
            float bd = best[mt][j];
            int bi = besti[mt][j];
            #pragma unroll
            for (int mm = 1; mm <= 8; mm <<= 1) {
                const float od = __shfl_xor(bd, mm, 64);
                const int oi = __shfl_xor(bi, mm, 64);
                if (od < bd || (od == bd && oi < bi)) { bd = od; bi = oi; }
            }
            rbd[mt][j] = bd; rbi[mt][j] = bi;
        }
    }
    // ---- cross-warp combine: wc==1 deposits, wc==0 merges + writes + publishes ----
    __syncthreads();
    #pragma unroll
    for (int mt = 0; mt < 4; ++mt)
        #pragma unroll
        for (int j = 0; j < 4; ++j)
            if (wc == 1 && r15 == 0) {
                const int trow = wr * 64 + mt * 16 + g * 4 + j;
                redD[trow] = rbd[mt][j];
                redI[trow] = rbi[mt][j];
            }
    __syncthreads();
    #pragma unroll
    for (int mt = 0; mt < 4; ++mt)
        #pragma unroll
        for (int j = 0; j < 4; ++j)
            if (wc == 0 && r15 == 0) {
                const int trow = wr * 64 + mt * 16 + g * 4 + j;
                float bd = rbd[mt][j];
                int bi = rbi[mt][j];
                const float od = redD[trow];
                const int oi = redI[trow];
                if (od < bd || (od == bd && oi < bi)) { bd = od; bi = oi; }
                const int n = tokbase + trow;
                idx_int[n] = bi;
                idx_f[n] = (float)bi;
                atomicAdd(&hist[bi], 1);
                redI[trow] = bi;      // publish merged idx for resid epilogue
            }
    __syncthreads();

    // ---- fused residual update + loss (2 threads/row, 128 f32 each) ----
    {
        const int n = tokbase + arow;
        const int kk = redI[arow];
        const float4* rs = (const float4*)(Rsrc + (size_t)n * D_DIM + ah * 128);
        const float4* qs = (const float4*)(cb_s + (size_t)kk * D_DIM + ah * 128);
        float4* rd = (float4*)(Rbuf + (size_t)n * D_DIM + ah * 128);
        float lp = 0.0f;
        if (mode == 0) {
            #pragma unroll 4
            for (int j = 0; j < 32; ++j) {
                const float4 r4 = rs[j];
                const float4 q4 = qs[j];
                float4 o;
                o.x = r4.x - q4.x; o.y = r4.y - q4.y;
                o.z = r4.z - q4.z; o.w = r4.w - q4.w;
                lp += o.x * o.x + o.y * o.y + o.z * o.z + o.w * o.w;
                rd[j] = o;
            }
        } else {
            const float4* zs = (const float4*)(z + (size_t)n * D_DIM + ah * 128);
            float4* os = (float4*)(zq + (size_t)n * D_DIM + ah * 128);
            #pragma unroll 4
            for (int j = 0; j < 32; ++j) {
                const float4 r4 = rs[j];
                const float4 q4 = qs[j];
                const float4 z4 = zs[j];
                float4 o;
                o.x = r4.x - q4.x; o.y = r4.y - q4.y;
                o.z = r4.z - q4.z; o.w = r4.w - q4.w;
                lp += o.x * o.x + o.y * o.y + o.z * o.z + o.w * o.w;
                rd[j] = o;
                float4 zo;
                zo.x = z4.x - o.x; zo.y = z4.y - o.y;
                zo.z = z4.z - o.z; zo.w = z4.w - o.w;
                os[j] = zo;
            }
        }
        #pragma unroll
        for (int off = 32; off > 0; off >>= 1) lp += __shfl_down(lp, off, 64);
        if (lane == 0) redD[w] = lp;
        __syncthreads();
        if (tid == 0) atomicAdd(loss_s, (redD[0] + redD[1]) + (redD[2] + redD[3]));
    }
}

// ---------- prefix sum over 1024 bins (1 block, 256 threads) ----------
__global__ void k_scan(const int* __restrict__ hist, int* __restrict__ off,
                       int* __restrict__ cursor) {
    __shared__ int tsum[256];
    const int t = threadIdx.x;
    int v[4], s = 0;
    #pragma unroll
    for (int j = 0; j < 4; ++j) { v[j] = hist[t * 4 + j]; s += v[j]; }
    tsum[t] = s;
    __syncthreads();
    if (t == 0) {
        int run = 0;
        for (int i = 0; i < 256; ++i) { int x = tsum[i]; tsum[i] = run; run += x; }
    }
    __syncthreads();
    int run = tsum[t];
    #pragma unroll
    for (int j = 0; j < 4; ++j) {
        off[t * 4 + j] = run;
        cursor[t * 4 + j] = run;
        run += v[j];
    }
    if (t == 255) off[K_CODES] = run;
}

// ---------- scatter tokens into per-code lists ----------
__global__ void k_scatter(const int* __restrict__ idx_s, int* __restrict__ cursor,
                          int* __restrict__ perm, const int Nt) {
    for (int n = blockIdx.x * blockDim.x + threadIdx.x; n < Nt; n += gridDim.x * blockDim.x) {
        const int pos = atomicAdd(&cursor[idx_s[n]], 1);
        perm[pos] = n;
    }
}

// ---------- balanced chunked segment sum over sorted tokens (post-sub residuals) ----------
__global__ __launch_bounds__(256) void k_chunksum(const float* __restrict__ Rnew,
                                                  const int* __restrict__ perm,
                                                  const int* __restrict__ idx_s,
                                                  float* __restrict__ accum) {
    __shared__ int pl[CHUNK];
    __shared__ int kl[CHUNK];
    const int t = threadIdx.x;
    const int base = blockIdx.x * CHUNK;
    if (t < CHUNK) pl[t] = perm[base + t];
    __syncthreads();
    if (t < CHUNK) kl[t] = idx_s[pl[t]];
    __syncthreads();
    float acc = 0.0f;
    int cur = kl[0];
    for (int m = 0; m < CHUNK; ++m) {
        const int k = kl[m];               // wave-uniform
        if (k != cur) {
            atomicAdd(&accum[(size_t)cur * D_DIM + t], acc);
            acc = 0.0f;
            cur = k;
        }
        acc += Rnew[(size_t)pl[m] * D_DIM + t];
    }
    atomicAdd(&accum[(size_t)cur * D_DIM + t], acc);
}

// ---------- EMA finalize: compensate post-sub sums (pre = post + cnt*cb) ----------
__global__ void k_ema_final(const float* __restrict__ accum,
                            const int* __restrict__ hist,
                            const float* __restrict__ cb_s,
                            const float* __restrict__ N_in,     // + s*K
                            const float* __restrict__ zavg_in,  // + s*K*D
                            float* __restrict__ out_N,
                            float* __restrict__ out_zavg,
                            float* __restrict__ out_cb) {
    const int k = blockIdx.x, t = threadIdx.x;
    const float cnt = (float)hist[k];
    const float presum = accum[(size_t)k * D_DIM + t] + cnt * cb_s[(size_t)k * D_DIM + t];
    const float zk = presum / (cnt + EPS_F);
    const float Ns = DECAY * N_in[k] + (1.0f - DECAY) * cnt;
    const float za = DECAY * zavg_in[(size_t)k * D_DIM + t] + (1.0f - DECAY) * zk;
    out_zavg[(size_t)k * D_DIM + t] = za;
    out_cb[(size_t)k * D_DIM + t] = za / (Ns + EPS_F);
    if (t == 0) out_N[k] = Ns;
}

__global__ void k_loss_final(const float* __restrict__ loss_acc,
                             float* __restrict__ out_loss, const float meanDiv) {
    if (threadIdx.x == 0 && blockIdx.x == 0) {
        float loss = 0.0f;
        #pragma unroll
        for (int s = 0; s < S_STAGES; ++s) loss = loss + BETA * (loss_acc[s] / meanDiv);
        out_loss[0] = loss;
    }
}

extern "C" void kernel_launch(void* const* d_in, const int* in_sizes, int n_in,
                              void* d_out, int out_size, void* d_ws, size_t ws_size,
                              hipStream_t stream)
{
    const float* z = (const float*)d_in[0];
    const float* cb = (const float*)d_in[1];
    const float* N_in = (const float*)d_in[2];
    const float* zavg = (const float*)d_in[3];
    float* out = (float*)d_out;

    const int Nt = in_sizes[0] / D_DIM;      // 65536

    // ---- workspace layout (~75.7 MB) ----
    char* wp = (char*)d_ws;
    int* idx_ws = (int*)wp;                 wp += (size_t)S_STAGES * Nt * 4;
    int* perm   = (int*)wp;                 wp += (size_t)Nt * 4;
    int* hist   = (int*)wp;                 wp += K_CODES * 4;
    int* cursor = (int*)wp;                 wp += K_CODES * 4;
    int* off    = (int*)wp;                 wp += (K_CODES + 8) * 4;
    float* sumsq = (float*)wp;              wp += S_STAGES * K_CODES * 4;
    float* lossa = (float*)wp;              wp += 64;
    float* accum = (float*)wp;              wp += (size_t)K_CODES * D_DIM * 4;
    unsigned short* Bh = (unsigned short*)wp; wp += (size_t)S_STAGES * K_CODES * D_DIM * 2;
    unsigned short* Bm = (unsigned short*)wp; wp += (size_t)S_STAGES * K_CODES * D_DIM * 2;
    unsigned short* Bl = (unsigned short*)wp; wp += (size_t)S_STAGES * K_CODES * D_DIM * 2;
    wp = (char*)(((size_t)wp + 255) & ~(size_t)255);
    float* Rbuf = (float*)wp;               // Nt * D fp32 (64 MB)

    const size_t ZQ_OFF = 0;
    const size_t LOSS_OFF = (size_t)Nt * D_DIM;
    const size_t IDX_OFF = LOSS_OFF + 1;
    const size_t CB_OFF = IDX_OFF + (size_t)S_STAGES * Nt;
    const size_t N_OFF = CB_OFF + (size_t)S_STAGES * K_CODES * D_DIM;
    const size_t ZAVG_OFF = N_OFF + (size_t)S_STAGES * K_CODES;

    hipMemsetAsync(lossa, 0, 64, stream);
    k_sumsq<<<(S_STAGES * K_CODES + 255) / 256, 256, 0, stream>>>(cb, sumsq);
    k_splitB<<<1024, 256, 0, stream>>>(cb, Bh, Bm, Bl);

    for (int s = 0; s < S_STAGES; ++s) {
        const float* Rsrc = (s == 0) ? z : Rbuf;
        const float* cb_s = cb + (size_t)s * K_CODES * D_DIM;
        int* idx_s = idx_ws + (size_t)s * Nt;
        hipMemsetAsync(hist, 0, K_CODES * 4, stream);
        hipMemsetAsync(accum, 0, (size_t)K_CODES * D_DIM * 4, stream);
        k_argmin_mfma<<<Nt / 128, 256, 0, stream>>>(
            Rsrc, z, cb_s, Bh, Bm, Bl, sumsq + s * K_CODES, s,
            idx_s, out + IDX_OFF + (size_t)s * Nt, hist,
            Rbuf, out + ZQ_OFF, lossa + s, (s == 3) ? 1 : 0);
        k_scan<<<1, 256, 0, stream>>>(hist, off, cursor);
        k_scatter<<<64, 256, 0, stream>>>(idx_s, cursor, perm, Nt);
        k_chunksum<<<Nt / CHUNK, 256, 0, stream>>>(Rbuf, perm, idx_s, accum);
        k_ema_final<<<K_CODES, 256, 0, stream>>>(
            accum, hist, cb_s,
            N_in + s * K_CODES, zavg + (size_t)s * K_CODES * D_DIM,
            out + N_OFF + s * K_CODES,
            out + ZAVG_OFF + (size_t)s * K_CODES * D_DIM,
            out + CB_OFF + (size_t)s * K_CODES * D_DIM);
    }
    k_loss_final<<<1, 64, 0, stream>>>(lossa, out + LOSS_OFF, (float)((size_t)Nt * D_DIM));
}